// Round 6
// baseline (428.241 us; speedup 1.0000x reference)
//
#include <hip/hip_runtime.h>
#include <hip/hip_bf16.h>
#include <stdint.h>

#define OUT_CH 128
#define EPSV 1e-10f

typedef __attribute__((ext_vector_type(4))) float f32x4;
typedef __attribute__((ext_vector_type(8))) short bf16x8;

__device__ __forceinline__ ushort f2bf(float f) {
    union { float f; unsigned u; } a; a.f = f;
    unsigned u = a.u;
    unsigned r = (u + 0x7fffu + ((u >> 16) & 1u)) >> 16;  // RNE
    return (ushort)r;
}

__device__ __forceinline__ float bflo(unsigned u) { return __uint_as_float(u << 16); }
__device__ __forceinline__ float bfhi(unsigned u) { return __uint_as_float(u & 0xffff0000u); }

// ------ hist + one-time weight bf16 conversion + emb bf16 conversion (fused) ------
// blocks [0,HB): histogram of targets
// blocks [HB,HB+16): weight f32->bf16 into Wb
// blocks [HB+16, HB+16+EB): emb f32->bf16 into embb (std half of d_out)
__global__ __launch_bounds__(256) void hist_convert_kernel(
    const int* __restrict__ eidx, int* __restrict__ cnt, int E, int HB, int EB,
    const float* __restrict__ locw, const float* __restrict__ stdw,
    int4* __restrict__ Wb, const float* __restrict__ emb, int4* __restrict__ embb4)
{
    int b = blockIdx.x;
    if (b < HB) {
        int e = b * 256 + threadIdx.x;
        if (e < E) atomicAdd(&cnt[eidx[E + e]], 1);
    } else if (b < HB + 16) {
        int q = (b - HB) * 256 + threadIdx.x;   // 0..4095: 256 rows x 16 chunks
        int r = q >> 4;
        int c = q & 15;
        const float* src = (r < 128) ? (locw + r * 128 + c * 8)
                                     : (stdw + (r - 128) * 128 + c * 8);
        float4 u0 = *reinterpret_cast<const float4*>(src);
        float4 u1 = *reinterpret_cast<const float4*>(src + 4);
        unsigned p0 = (unsigned)f2bf(u0.x) | ((unsigned)f2bf(u0.y) << 16);
        unsigned p1 = (unsigned)f2bf(u0.z) | ((unsigned)f2bf(u0.w) << 16);
        unsigned p2 = (unsigned)f2bf(u1.x) | ((unsigned)f2bf(u1.y) << 16);
        unsigned p3 = (unsigned)f2bf(u1.z) | ((unsigned)f2bf(u1.w) << 16);
        Wb[q] = make_int4((int)p0, (int)p1, (int)p2, (int)p3);
    } else {
        int idx8 = (b - HB - 16) * 256 + threadIdx.x;   // one 8-float chunk
        const float4* e4 = (const float4*)emb;
        float4 u0 = e4[(size_t)idx8 * 2];
        float4 u1 = e4[(size_t)idx8 * 2 + 1];
        unsigned p0 = (unsigned)f2bf(u0.x) | ((unsigned)f2bf(u0.y) << 16);
        unsigned p1 = (unsigned)f2bf(u0.z) | ((unsigned)f2bf(u0.w) << 16);
        unsigned p2 = (unsigned)f2bf(u1.x) | ((unsigned)f2bf(u1.y) << 16);
        unsigned p3 = (unsigned)f2bf(u1.z) | ((unsigned)f2bf(u1.w) << 16);
        embb4[idx8] = make_int4((int)p0, (int)p1, (int)p2, (int)p3);
    }
}

// ------ single-launch exclusive scan: cursor[i] = sum(cnt[0..i)) ------
// One block, 1024 threads; each thread owns a contiguous chunk of ~N/1024.
__global__ __launch_bounds__(1024) void scan_kernel(
    const int* __restrict__ cnt, int* __restrict__ cursor, int N)
{
    __shared__ int lds[1024];
    int t = threadIdx.x;
    int CH = (N + 1023) >> 10;
    int s = t * CH;
    int e = s + CH; if (e > N) e = N;
    int local = 0;
    for (int i = s; i < e; ++i) local += cnt[i];
    lds[t] = local; __syncthreads();
    #pragma unroll
    for (int d = 1; d < 1024; d <<= 1) {
        int x = (t >= d) ? lds[t - d] : 0;
        __syncthreads();
        lds[t] += x;
        __syncthreads();
    }
    int run = lds[t] - local;   // exclusive prefix of this chunk
    for (int i = s; i < e; ++i) { cursor[i] = run; run += cnt[i]; }
}

__global__ __launch_bounds__(256) void fill_kernel(
    const int* __restrict__ eidx, const float* __restrict__ enorm,
    int* __restrict__ cursor, int2* __restrict__ srcw, int E)
{
    int e = blockIdx.x * 256 + threadIdx.x;
    if (e >= E) return;
    int t = eidx[E + e];
    int s = eidx[e];
    float w = enorm[e];
    int pos = atomicAdd(&cursor[t], 1);
    srcw[pos] = make_int2(s, __float_as_int(w));
}

// ---------------- gather: segment-sum over bf16 emb into bf16 ptr rows ----------------
// TWO nodes per wave: half-wave (32 lanes) per node, lane owns 4 channels (8 B).
// Doubles independent load chains per wave, halves wave count. bf16 ptr row r
// stored at 512B stride (first 256B) in the loc half (gemm-wave-exclusive).
__global__ __launch_bounds__(256) void gather_kernel(
    const uint2* __restrict__ embb2, const int* __restrict__ cursor,
    const int* __restrict__ cnt, const int2* __restrict__ srcw,
    uint2* __restrict__ ptrb2, int N)
{
    int h = (blockIdx.x * 256 + threadIdx.x) >> 5;   // half-wave id = node id
    if (h >= N) return;
    int lane = threadIdx.x & 31;
    int c = cnt[h];
    int o = cursor[h] - c;      // cursor == segment end after fill
    float a0 = 0.f, a1 = 0.f, a2 = 0.f, a3 = 0.f;
    int j = 0;
    for (; j + 4 <= c; j += 4) {
        int2 p0 = srcw[o + j + 0];
        int2 p1 = srcw[o + j + 1];
        int2 p2 = srcw[o + j + 2];
        int2 p3 = srcw[o + j + 3];
        uint2 v0 = embb2[(size_t)p0.x * 32 + lane];
        uint2 v1 = embb2[(size_t)p1.x * 32 + lane];
        uint2 v2 = embb2[(size_t)p2.x * 32 + lane];
        uint2 v3 = embb2[(size_t)p3.x * 32 + lane];
        float w0 = __int_as_float(p0.y), w1 = __int_as_float(p1.y);
        float w2 = __int_as_float(p2.y), w3 = __int_as_float(p3.y);
        a0 += bflo(v0.x) * w0 + bflo(v1.x) * w1 + bflo(v2.x) * w2 + bflo(v3.x) * w3;
        a1 += bfhi(v0.x) * w0 + bfhi(v1.x) * w1 + bfhi(v2.x) * w2 + bfhi(v3.x) * w3;
        a2 += bflo(v0.y) * w0 + bflo(v1.y) * w1 + bflo(v2.y) * w2 + bflo(v3.y) * w3;
        a3 += bfhi(v0.y) * w0 + bfhi(v1.y) * w1 + bfhi(v2.y) * w2 + bfhi(v3.y) * w3;
    }
    for (; j < c; ++j) {
        int2 p = srcw[o + j];
        float w = __int_as_float(p.y);
        uint2 v = embb2[(size_t)p.x * 32 + lane];
        a0 += bflo(v.x) * w;
        a1 += bfhi(v.x) * w;
        a2 += bflo(v.y) * w;
        a3 += bfhi(v.y) * w;
    }
    uint2 r;
    r.x = (unsigned)f2bf(a0) | ((unsigned)f2bf(a1) << 16);
    r.y = (unsigned)f2bf(a2) | ((unsigned)f2bf(a3) << 16);
    ptrb2[(size_t)h * 64 + lane] = r;   // 512B row stride, first 256B used
}

// ---------------- GEMM + bias + softplus, two-pass (loc then std) ----------------
// A (bf16 ptr, 512B row stride) lives in the loc half; each wave loads its 32
// rows into registers up front, then overwrites only those rows (loc pass) and
// the std half (std pass). 32 KiB LDS per pass -> 4 blocks/CU.
__global__ __launch_bounds__(256, 4) void gemm_kernel(
    const int4* __restrict__ Wb, const float* __restrict__ locb,
    const float* __restrict__ stdb, float* __restrict__ out, int N)
{
    __shared__ ushort Wt[128 * 128];   // 32 KiB: one weight matrix (row = out col)
    const int t = threadIdx.x;
    const int wave = t >> 6;
    const int lane = t & 63;
    const int grp = lane >> 4;
    const int l16 = lane & 15;
    const int base = blockIdx.x * 128 + wave * 32;

    const ushort* ptrb = (const ushort*)out;   // bf16 row r at ushort offset r*256
    int r0 = base + l16;      if (r0 > N - 1) r0 = N - 1;
    int r1 = base + 16 + l16; if (r1 > N - 1) r1 = N - 1;

    bf16x8 a0[4], a1[4];
    #pragma unroll
    for (int s = 0; s < 4; ++s) {
        a0[s] = *reinterpret_cast<const bf16x8*>(ptrb + (size_t)r0 * 256 + s * 32 + grp * 8);
        a1[s] = *reinterpret_cast<const bf16x8*>(ptrb + (size_t)r1 * 256 + s * 32 + grp * 8);
    }

    #pragma unroll
    for (int h = 0; h < 2; ++h) {
        if (h) __syncthreads();          // all pass-A LDS reads done before overwrite
        #pragma unroll
        for (int i = 0; i < 8; ++i) {
            int q = i * 256 + t;         // 0..2047 = 128 rows x 16 chunks
            int r = q >> 4;
            int c = q & 15;
            *reinterpret_cast<int4*>(&Wt[r * 128 + ((c ^ (r & 15)) << 3)]) =
                Wb[(h * 128 + r) * 16 + c];
        }
        __syncthreads();

        f32x4 acc0[8], acc1[8];
        #pragma unroll
        for (int j = 0; j < 8; ++j) {
            acc0[j] = (f32x4){0.f, 0.f, 0.f, 0.f};
            acc1[j] = (f32x4){0.f, 0.f, 0.f, 0.f};
        }

        #pragma unroll
        for (int j = 0; j < 8; ++j) {
            int cb = (j * 16 + l16) * 128;
            #pragma unroll
            for (int s = 0; s < 4; ++s) {
                int c = s * 4 + grp;
                bf16x8 bfr = *reinterpret_cast<const bf16x8*>(&Wt[cb + ((c ^ l16) << 3)]);
                acc0[j] = __builtin_amdgcn_mfma_f32_16x16x32_bf16(a0[s], bfr, acc0[j], 0, 0, 0);
                acc1[j] = __builtin_amdgcn_mfma_f32_16x16x32_bf16(a1[s], bfr, acc1[j], 0, 0, 0);
            }
        }

        // C/D map: col = lane&15, row = grp*4 + reg (m89-verified)
        float* dst = h ? (out + (size_t)N * OUT_CH) : out;
        #pragma unroll
        for (int j = 0; j < 8; ++j) {
            int col = j * 16 + l16;
            float bias = h ? stdb[col] : locb[col];
            #pragma unroll
            for (int tile = 0; tile < 2; ++tile) {
                #pragma unroll
                for (int rg = 0; rg < 4; ++rg) {
                    int node = base + tile * 16 + grp * 4 + rg;
                    if (node < N) {
                        float x = (tile ? acc1[j][rg] : acc0[j][rg]) + bias;
                        if (h) x = __logf(1.0f + __expf(x)) + EPSV;  // |x| small: exact enough
                        dst[(size_t)node * OUT_CH + col] = x;
                    }
                }
            }
        }
    }
}

extern "C" void kernel_launch(void* const* d_in, const int* in_sizes, int n_in,
                              void* d_out, int out_size, void* d_ws, size_t ws_size,
                              hipStream_t stream) {
    const float* emb  = (const float*)d_in[0];
    const float* locw = (const float*)d_in[1];
    const float* locb = (const float*)d_in[2];
    const float* stdw = (const float*)d_in[3];
    const float* stdb = (const float*)d_in[4];
    const int*   eidx = (const int*)d_in[5];
    const float* enorm= (const float*)d_in[6];
    float* out = (float*)d_out;

    const int N = in_sizes[0] / OUT_CH;   // 100000
    const int E = in_sizes[6];            // 600000
    const int HB = (E + 255) / 256;       // 2344
    const int EB = (N * (OUT_CH / 8) + 255) / 256;  // emb 8-float chunks / 256

    // workspace layout (~5.7 MB)
    int* cnt    = (int*)d_ws;            // N
    int* cursor = cnt + N;               // N
    int2* srcw  = (int2*)(((uintptr_t)(cursor + N) + 255) & ~(uintptr_t)255);  // E
    int4* Wb    = (int4*)(((uintptr_t)(srcw + E) + 255) & ~(uintptr_t)255);    // 64 KiB

    // bf16 emb lives in the std half of out (gemm overwrites it at the very end)
    unsigned* embb = (unsigned*)(out + (size_t)N * OUT_CH);

    hipMemsetAsync(cnt, 0, (size_t)N * sizeof(int), stream);

    hist_convert_kernel<<<HB + 16 + EB, 256, 0, stream>>>(
        eidx, cnt, E, HB, EB, locw, stdw, Wb, emb, (int4*)embb);
    scan_kernel<<<1, 1024, 0, stream>>>(cnt, cursor, N);
    fill_kernel<<<(E + 255) / 256, 256, 0, stream>>>(eidx, enorm, cursor, srcw, E);

    uint2* ptrb2 = (uint2*)out;   // bf16 ptr rows, 512B stride, loc half
    long gthreads = (long)N * 32;
    gather_kernel<<<(int)((gthreads + 255) / 256), 256, 0, stream>>>(
        (const uint2*)embb, cursor, cnt, srcw, ptrb2, N);

    int nblocks = (N + 127) / 128;
    gemm_kernel<<<nblocks, 256, 0, stream>>>(Wb, locb, stdb, out, N);
}

// Round 7
// 279.765 us; speedup vs baseline: 1.5307x; 1.5307x over previous
//
#include <hip/hip_runtime.h>
#include <hip/hip_bf16.h>
#include <stdint.h>

#define OUT_CH 128
#define EPSV 1e-10f

typedef __attribute__((ext_vector_type(4))) float f32x4;
typedef __attribute__((ext_vector_type(8))) short bf16x8;

__device__ __forceinline__ ushort f2bf(float f) {
    union { float f; unsigned u; } a; a.f = f;
    unsigned u = a.u;
    unsigned r = (u + 0x7fffu + ((u >> 16) & 1u)) >> 16;  // RNE
    return (ushort)r;
}

__device__ __forceinline__ float bflo(unsigned u) { return __uint_as_float(u << 16); }
__device__ __forceinline__ float bfhi(unsigned u) { return __uint_as_float(u & 0xffff0000u); }

// ------ hist + one-time weight bf16 conversion + emb bf16 conversion (fused) ------
// blocks [0,HB): histogram of targets
// blocks [HB,HB+16): weight f32->bf16 into Wb
// blocks [HB+16, HB+16+EB): emb f32->bf16 into embb (std half of d_out)
__global__ __launch_bounds__(256) void hist_convert_kernel(
    const int* __restrict__ eidx, int* __restrict__ cnt, int E, int HB, int EB,
    const float* __restrict__ locw, const float* __restrict__ stdw,
    int4* __restrict__ Wb, const float* __restrict__ emb, int4* __restrict__ embb4)
{
    int b = blockIdx.x;
    if (b < HB) {
        int e = b * 256 + threadIdx.x;
        if (e < E) atomicAdd(&cnt[eidx[E + e]], 1);
    } else if (b < HB + 16) {
        int q = (b - HB) * 256 + threadIdx.x;   // 0..4095: 256 rows x 16 chunks
        int r = q >> 4;
        int c = q & 15;
        const float* src = (r < 128) ? (locw + r * 128 + c * 8)
                                     : (stdw + (r - 128) * 128 + c * 8);
        float4 u0 = *reinterpret_cast<const float4*>(src);
        float4 u1 = *reinterpret_cast<const float4*>(src + 4);
        unsigned p0 = (unsigned)f2bf(u0.x) | ((unsigned)f2bf(u0.y) << 16);
        unsigned p1 = (unsigned)f2bf(u0.z) | ((unsigned)f2bf(u0.w) << 16);
        unsigned p2 = (unsigned)f2bf(u1.x) | ((unsigned)f2bf(u1.y) << 16);
        unsigned p3 = (unsigned)f2bf(u1.z) | ((unsigned)f2bf(u1.w) << 16);
        Wb[q] = make_int4((int)p0, (int)p1, (int)p2, (int)p3);
    } else {
        int idx8 = (b - HB - 16) * 256 + threadIdx.x;   // one 8-float chunk
        const float4* e4 = (const float4*)emb;
        float4 u0 = e4[(size_t)idx8 * 2];
        float4 u1 = e4[(size_t)idx8 * 2 + 1];
        unsigned p0 = (unsigned)f2bf(u0.x) | ((unsigned)f2bf(u0.y) << 16);
        unsigned p1 = (unsigned)f2bf(u0.z) | ((unsigned)f2bf(u0.w) << 16);
        unsigned p2 = (unsigned)f2bf(u1.x) | ((unsigned)f2bf(u1.y) << 16);
        unsigned p3 = (unsigned)f2bf(u1.z) | ((unsigned)f2bf(u1.w) << 16);
        embb4[idx8] = make_int4((int)p0, (int)p1, (int)p2, (int)p3);
    }
}

__device__ __forceinline__ int block_exscan256(int v, int* lds, int* totalOut) {
    int t = threadIdx.x;
    lds[t] = v; __syncthreads();
    #pragma unroll
    for (int d = 1; d < 256; d <<= 1) {
        int x = (t >= d) ? lds[t - d] : 0;
        __syncthreads();
        lds[t] += x;
        __syncthreads();
    }
    int inc = lds[t];
    int tot = lds[255];
    __syncthreads();
    *totalOut = tot;
    return inc - v;
}

// block sums over 1024-element tiles
__global__ __launch_bounds__(256) void block_sum_kernel(
    const int* __restrict__ cnt, int* __restrict__ bsum, int N)
{
    __shared__ int lds[256];
    int base = blockIdx.x * 1024;
    int local = 0;
    #pragma unroll
    for (int k = 0; k < 4; ++k) {
        int idx = base + threadIdx.x * 4 + k;
        local += (idx < N) ? cnt[idx] : 0;
    }
    lds[threadIdx.x] = local; __syncthreads();
    for (int d = 128; d > 0; d >>= 1) {
        if (threadIdx.x < d) lds[threadIdx.x] += lds[threadIdx.x + d];
        __syncthreads();
    }
    if (threadIdx.x == 0) bsum[blockIdx.x] = lds[0];
}

// single-block exclusive scan of block sums (NB <= 256)
__global__ __launch_bounds__(256) void top_scan_kernel(
    const int* __restrict__ bsum, int* __restrict__ bofs, int NB)
{
    __shared__ int lds[256];
    int t = threadIdx.x;
    int v = (t < NB) ? bsum[t] : 0;
    int total;
    int ex = block_exscan256(v, lds, &total);
    if (t < NB) bofs[t] = ex;
}

// exclusive prefix -> cursor (start offsets); after fill, cursor = segment end
__global__ __launch_bounds__(256) void scan_final_kernel(
    const int* __restrict__ cnt, const int* __restrict__ bofs,
    int* __restrict__ cursor, int N)
{
    __shared__ int lds[256];
    int base = blockIdx.x * 1024;
    int c[4]; int local = 0;
    #pragma unroll
    for (int k = 0; k < 4; ++k) {
        int idx = base + threadIdx.x * 4 + k;
        c[k] = (idx < N) ? cnt[idx] : 0;
        local += c[k];
    }
    int total;
    int ex = block_exscan256(local, lds, &total);
    int run = bofs[blockIdx.x] + ex;
    #pragma unroll
    for (int k = 0; k < 4; ++k) {
        int idx = base + threadIdx.x * 4 + k;
        if (idx < N) { cursor[idx] = run; run += c[k]; }
    }
}

__global__ __launch_bounds__(256) void fill_kernel(
    const int* __restrict__ eidx, const float* __restrict__ enorm,
    int* __restrict__ cursor, int2* __restrict__ srcw, int E)
{
    int e = blockIdx.x * 256 + threadIdx.x;
    if (e >= E) return;
    int t = eidx[E + e];
    int s = eidx[e];
    float w = enorm[e];
    int pos = atomicAdd(&cursor[t], 1);
    srcw[pos] = make_int2(s, __float_as_int(w));
}

// ---------------- gather: segment-sum over bf16 emb into bf16 ptr rows ----------------
// FOUR nodes per wave: 16 lanes per node, lane owns 8 channels (16 B uint4).
// 4 independent load chains per wave + dwordx4 loads. bf16 ptr row r stored at
// 512B stride (first 256B) in the loc half (gemm-wave-exclusive region).
__global__ __launch_bounds__(256) void gather_kernel(
    const uint4* __restrict__ embb4, const int* __restrict__ cursor,
    const int* __restrict__ cnt, const int2* __restrict__ srcw,
    uint4* __restrict__ ptrb4, int N)
{
    int q = (blockIdx.x * 256 + threadIdx.x) >> 4;   // quarter-wave id = node id
    if (q >= N) return;
    int l16 = threadIdx.x & 15;
    int c = cnt[q];
    int o = cursor[q] - c;      // cursor == segment end after fill
    float a0 = 0.f, a1 = 0.f, a2 = 0.f, a3 = 0.f;
    float a4 = 0.f, a5 = 0.f, a6 = 0.f, a7 = 0.f;
    int j = 0;
    for (; j + 2 <= c; j += 2) {
        int2 p0 = srcw[o + j + 0];
        int2 p1 = srcw[o + j + 1];
        uint4 v0 = embb4[(size_t)p0.x * 16 + l16];
        uint4 v1 = embb4[(size_t)p1.x * 16 + l16];
        float w0 = __int_as_float(p0.y), w1 = __int_as_float(p1.y);
        a0 += bflo(v0.x) * w0 + bflo(v1.x) * w1;
        a1 += bfhi(v0.x) * w0 + bfhi(v1.x) * w1;
        a2 += bflo(v0.y) * w0 + bflo(v1.y) * w1;
        a3 += bfhi(v0.y) * w0 + bfhi(v1.y) * w1;
        a4 += bflo(v0.z) * w0 + bflo(v1.z) * w1;
        a5 += bfhi(v0.z) * w0 + bfhi(v1.z) * w1;
        a6 += bflo(v0.w) * w0 + bflo(v1.w) * w1;
        a7 += bfhi(v0.w) * w0 + bfhi(v1.w) * w1;
    }
    if (j < c) {
        int2 p = srcw[o + j];
        uint4 v = embb4[(size_t)p.x * 16 + l16];
        float w = __int_as_float(p.y);
        a0 += bflo(v.x) * w;  a1 += bfhi(v.x) * w;
        a2 += bflo(v.y) * w;  a3 += bfhi(v.y) * w;
        a4 += bflo(v.z) * w;  a5 += bfhi(v.z) * w;
        a6 += bflo(v.w) * w;  a7 += bfhi(v.w) * w;
    }
    uint4 r;
    r.x = (unsigned)f2bf(a0) | ((unsigned)f2bf(a1) << 16);
    r.y = (unsigned)f2bf(a2) | ((unsigned)f2bf(a3) << 16);
    r.z = (unsigned)f2bf(a4) | ((unsigned)f2bf(a5) << 16);
    r.w = (unsigned)f2bf(a6) | ((unsigned)f2bf(a7) << 16);
    ptrb4[(size_t)q * 32 + l16] = r;   // 512B row stride, first 256B used
}

// ---------------- GEMM + bias + softplus, two-pass (loc then std) ----------------
// A (bf16 ptr, 512B row stride) lives in the loc half; each wave loads its 32
// rows into registers up front, then overwrites only those rows (loc pass) and
// the std half (std pass). 32 KiB LDS per pass -> 4 blocks/CU.
__global__ __launch_bounds__(256, 4) void gemm_kernel(
    const int4* __restrict__ Wb, const float* __restrict__ locb,
    const float* __restrict__ stdb, float* __restrict__ out, int N)
{
    __shared__ ushort Wt[128 * 128];   // 32 KiB: one weight matrix (row = out col)
    const int t = threadIdx.x;
    const int wave = t >> 6;
    const int lane = t & 63;
    const int grp = lane >> 4;
    const int l16 = lane & 15;
    const int base = blockIdx.x * 128 + wave * 32;

    const ushort* ptrb = (const ushort*)out;   // bf16 row r at ushort offset r*256
    int r0 = base + l16;      if (r0 > N - 1) r0 = N - 1;
    int r1 = base + 16 + l16; if (r1 > N - 1) r1 = N - 1;

    bf16x8 a0[4], a1[4];
    #pragma unroll
    for (int s = 0; s < 4; ++s) {
        a0[s] = *reinterpret_cast<const bf16x8*>(ptrb + (size_t)r0 * 256 + s * 32 + grp * 8);
        a1[s] = *reinterpret_cast<const bf16x8*>(ptrb + (size_t)r1 * 256 + s * 32 + grp * 8);
    }

    #pragma unroll
    for (int h = 0; h < 2; ++h) {
        if (h) __syncthreads();          // all pass-A LDS reads done before overwrite
        #pragma unroll
        for (int i = 0; i < 8; ++i) {
            int q = i * 256 + t;         // 0..2047 = 128 rows x 16 chunks
            int r = q >> 4;
            int c = q & 15;
            *reinterpret_cast<int4*>(&Wt[r * 128 + ((c ^ (r & 15)) << 3)]) =
                Wb[(h * 128 + r) * 16 + c];
        }
        __syncthreads();

        f32x4 acc0[8], acc1[8];
        #pragma unroll
        for (int j = 0; j < 8; ++j) {
            acc0[j] = (f32x4){0.f, 0.f, 0.f, 0.f};
            acc1[j] = (f32x4){0.f, 0.f, 0.f, 0.f};
        }

        #pragma unroll
        for (int j = 0; j < 8; ++j) {
            int cb = (j * 16 + l16) * 128;
            #pragma unroll
            for (int s = 0; s < 4; ++s) {
                int c = s * 4 + grp;
                bf16x8 bfr = *reinterpret_cast<const bf16x8*>(&Wt[cb + ((c ^ l16) << 3)]);
                acc0[j] = __builtin_amdgcn_mfma_f32_16x16x32_bf16(a0[s], bfr, acc0[j], 0, 0, 0);
                acc1[j] = __builtin_amdgcn_mfma_f32_16x16x32_bf16(a1[s], bfr, acc1[j], 0, 0, 0);
            }
        }

        // C/D map: col = lane&15, row = grp*4 + reg (m89-verified)
        float* dst = h ? (out + (size_t)N * OUT_CH) : out;
        #pragma unroll
        for (int j = 0; j < 8; ++j) {
            int col = j * 16 + l16;
            float bias = h ? stdb[col] : locb[col];
            #pragma unroll
            for (int tile = 0; tile < 2; ++tile) {
                #pragma unroll
                for (int rg = 0; rg < 4; ++rg) {
                    int node = base + tile * 16 + grp * 4 + rg;
                    if (node < N) {
                        float x = (tile ? acc1[j][rg] : acc0[j][rg]) + bias;
                        if (h) x = __logf(1.0f + __expf(x)) + EPSV;  // |x| small: exact enough
                        dst[(size_t)node * OUT_CH + col] = x;
                    }
                }
            }
        }
    }
}

extern "C" void kernel_launch(void* const* d_in, const int* in_sizes, int n_in,
                              void* d_out, int out_size, void* d_ws, size_t ws_size,
                              hipStream_t stream) {
    const float* emb  = (const float*)d_in[0];
    const float* locw = (const float*)d_in[1];
    const float* locb = (const float*)d_in[2];
    const float* stdw = (const float*)d_in[3];
    const float* stdb = (const float*)d_in[4];
    const int*   eidx = (const int*)d_in[5];
    const float* enorm= (const float*)d_in[6];
    float* out = (float*)d_out;

    const int N = in_sizes[0] / OUT_CH;   // 100000
    const int E = in_sizes[6];            // 600000
    const int NB = (N + 1023) / 1024;     // 98 (<= 256 required)
    const int HB = (E + 255) / 256;       // 2344
    const int EB = (N * (OUT_CH / 8) + 255) / 256;  // emb 8-float chunks / 256

    // workspace layout (~5.7 MB)
    int* cnt    = (int*)d_ws;            // N
    int* cursor = cnt + N;               // N
    int* bsum   = cursor + N;            // pad 256
    int* bofs   = bsum + 256;            // pad 256
    int2* srcw  = (int2*)(((uintptr_t)(bofs + 256) + 255) & ~(uintptr_t)255);  // E
    int4* Wb    = (int4*)(((uintptr_t)(srcw + E) + 255) & ~(uintptr_t)255);    // 64 KiB

    // bf16 emb lives in the std half of out (gemm overwrites it at the very end)
    unsigned* embb = (unsigned*)(out + (size_t)N * OUT_CH);

    hipMemsetAsync(cnt, 0, (size_t)N * sizeof(int), stream);

    hist_convert_kernel<<<HB + 16 + EB, 256, 0, stream>>>(
        eidx, cnt, E, HB, EB, locw, stdw, Wb, emb, (int4*)embb);
    block_sum_kernel<<<NB, 256, 0, stream>>>(cnt, bsum, N);
    top_scan_kernel<<<1, 256, 0, stream>>>(bsum, bofs, NB);
    scan_final_kernel<<<NB, 256, 0, stream>>>(cnt, bofs, cursor, N);
    fill_kernel<<<(E + 255) / 256, 256, 0, stream>>>(eidx, enorm, cursor, srcw, E);

    uint4* ptrb4 = (uint4*)out;   // bf16 ptr rows, 512B stride, loc half
    long gthreads = (long)N * 16;
    gather_kernel<<<(int)((gthreads + 255) / 256), 256, 0, stream>>>(
        (const uint4*)embb, cursor, cnt, srcw, ptrb4, N);

    int nblocks = (N + 127) / 128;
    gemm_kernel<<<nblocks, 256, 0, stream>>>(Wb, locb, stdb, out, N);
}